// Round 4
// baseline (123.609 us; speedup 1.0000x reference)
//
#include <hip/hip_runtime.h>
#include <hip/hip_bf16.h>
#include <math.h>

typedef __attribute__((ext_vector_type(8))) short bf16x8v;
typedef __attribute__((ext_vector_type(4))) float f32x4v;

namespace {

constexpr float PI_F      = 3.14159265358979323846f;
constexpr float TWO_PI_F  = 6.28318530717958647692f;
constexpr float INV_2PI_F = 0.15915494309189533577f;
constexpr float ZC_F      = 0.86602540378443864676f;

__device__ __constant__ float d_BOUNDS[8] = {0.1f, 0.2f, 0.4f, 0.6f, 0.75f,
                                             0.8660254037844386f, 0.92f, 0.97f};
__device__ __constant__ float d_PARITY[6] = {1.f, -1.f, 1.f, 1.f, -1.f, -1.f};
__device__ __constant__ int d_LEGAL[9][6] = {
    {0, 0, 0, 1, 1, 1},
    {1, 0, 1, 0, 1, 1},
    {1, 1, 1, 0, 1, 1},
    {0, 1, 0, 1, 1, 1},
    {1, 1, 1, 1, 1, 1},
    {0, 1, 0, 1, 1, 1},
    {0, 1, 0, 1, 0, 0},
    {0, 1, 1, 1, 0, 0},
    {0, 1, 1, 1, 0, 0}};

__device__ __forceinline__ float wave_sum(float v) {
#pragma unroll
  for (int o = 32; o > 0; o >>= 1) v += __shfl_xor(v, o, 64);
  return v;
}

__device__ __forceinline__ float gelu_exact(float x) {
  return 0.5f * x * (1.0f + erff(x * 0.70710678118654752440f));
}

__device__ __forceinline__ unsigned pkbf(float a, float b) {
  union { struct { __hip_bfloat16 x, y; } p; unsigned u; } t;
  t.p.x = __float2bfloat16(a);
  t.p.y = __float2bfloat16(b);
  return t.u;
}

__device__ __forceinline__ unsigned short f2b(float v) {
  const __hip_bfloat16 hb = __float2bfloat16(v);
  return __builtin_bit_cast(unsigned short, hb);
}

}  // namespace

// ---------------------------------------------------------------------------
// Prep: Aenc[o][k] = W_enc^T padded to [64][512] bf16 (coalesced writes).
// ---------------------------------------------------------------------------
__global__ __launch_bounds__(256) void prep_A_enc(
    const float* __restrict__ W_enc, unsigned short* __restrict__ A) {
  for (int t = blockIdx.x * 256 + threadIdx.x; t < 64 * 512; t += gridDim.x * 256) {
    const int o = t >> 9, k = t & 511;
    A[t] = f2b((o < 60) ? W_enc[k * 60 + o] : 0.f);
  }
}

// Aout[d][kk] bf16 [256][128]: kk<64 -> cos weights W_out[o][d], kk>=64 -> sin.
__global__ __launch_bounds__(256) void prep_A_out(
    const float* __restrict__ W_out, unsigned short* __restrict__ A) {
  for (int t = blockIdx.x * 256 + threadIdx.x; t < 256 * 128; t += gridDim.x * 256) {
    const int d = t >> 7, kk = t & 127, part = kk >> 6, o = kk & 63;
    A[t] = f2b((o < 60) ? W_out[(part * 60 + o) * 256 + d] : 0.f);
  }
}

// ---------------------------------------------------------------------------
// MFMA encoder: theta = pi*tanh(x @ W_enc + b_enc); D-fragment layout
// (col=lane&15=batch, row=16m+4g+r=osc). Writes theta + atomicAdd coh sum.
// 512 blocks x 64 thr (1 wave = 16 batch rows).
// ---------------------------------------------------------------------------
__global__ __launch_bounds__(64) void enc_mfma(
    const float* __restrict__ x, const unsigned short* __restrict__ Aenc,
    const float* __restrict__ b_enc, float* __restrict__ theta,
    float* __restrict__ slots) {
  const int tid = threadIdx.x;
  const int c = tid & 15, g = tid >> 4;
  const int b = blockIdx.x * 16 + c;
  const f32x4v z4 = {0.f, 0.f, 0.f, 0.f};
  f32x4v em[4] = {z4, z4, z4, z4};
  const float* xr = x + b * 512 + 8 * g;
#pragma unroll 4
  for (int kt = 0; kt < 16; ++kt) {
    const float4 u0 = *reinterpret_cast<const float4*>(xr + 32 * kt);
    const float4 u1 = *reinterpret_cast<const float4*>(xr + 32 * kt + 4);
    union { unsigned u[4]; bf16x8v v; } Bx;
    Bx.u[0] = pkbf(u0.x, u0.y); Bx.u[1] = pkbf(u0.z, u0.w);
    Bx.u[2] = pkbf(u1.x, u1.y); Bx.u[3] = pkbf(u1.z, u1.w);
#pragma unroll
    for (int m = 0; m < 4; ++m) {
      const bf16x8v Aa = *reinterpret_cast<const bf16x8v*>(
          Aenc + (16 * m + c) * 512 + 32 * kt + 8 * g);
      em[m] = __builtin_amdgcn_mfma_f32_16x16x32_bf16(Aa, Bx.v, em[m], 0, 0, 0);
    }
  }
  float th[4][4];
  float pc = 0.f, ps = 0.f;
#pragma unroll
  for (int m = 0; m < 4; ++m) {
    float4 be;
    if (m == 3 && g == 3) be = make_float4(0.f, 0.f, 0.f, 0.f);
    else be = *reinterpret_cast<const float4*>(b_enc + 16 * m + 4 * g);
    const float bea[4] = {be.x, be.y, be.z, be.w};
#pragma unroll
    for (int r = 0; r < 4; ++r) {
      const int o = 16 * m + 4 * g + r;
      th[m][r] = (o < 60) ? PI_F * tanhf(em[m][r] + bea[r]) : 0.f;
      pc += __cosf(th[m][r]);
      ps += __sinf(th[m][r]);
    }
  }
  pc += __shfl_xor(pc, 16); pc += __shfl_xor(pc, 32);
  ps += __shfl_xor(ps, 16); ps += __shfl_xor(ps, 32);
  const float mc = (pc - 4.f) * (1.f / 60.f);
  const float ms = ps * (1.f / 60.f);
  const float ch = sqrtf(mc * mc + ms * ms);
#pragma unroll
  for (int m = 0; m < 4; ++m) {
    if (m == 3 && g == 3) continue;
    *reinterpret_cast<float4*>(theta + b * 60 + 16 * m + 4 * g) =
        make_float4(th[m][0], th[m][1], th[m][2], th[m][3]);
  }
  const float tot = wave_sum(ch) * 0.25f;
  if (tid == 0) atomicAdd(slots + 0, tot);
}

// ---------------------------------------------------------------------------
// Fused decide+Kuramoto. 512 blocks x 64 thr; every wave redundantly runs the
// row-0 MLP (z from slots, feats from global theta row 0), then 10 MFMA steps.
// K loaded f32 -> bf16 frags in-kernel; ktot folded post-MFMA.
// ---------------------------------------------------------------------------
__global__ __launch_bounds__(64) void kura_mfma(
    float* __restrict__ theta, const float* __restrict__ noiseL,
    const float* __restrict__ K, const float* __restrict__ omega,
    const float* __restrict__ Kglob,
    const float* __restrict__ aplK, const float* __restrict__ aplOm,
    const float* __restrict__ W1, const float* __restrict__ b1,
    const float* __restrict__ W2, const float* __restrict__ b2,
    const float* __restrict__ W3, const float* __restrict__ b3,
    const float* __restrict__ prior, float* __restrict__ slots, int layer) {
  __shared__ float fe[64], hh[64], lg[8];
  const int tid = threadIdx.x;
  const int c = tid & 15, g = tid >> 4;
  const bool hi = (g >= 2);
  const int b = blockIdx.x * 16 + c;

  // ---- decide (redundant per wave) ----
  const float z = slots[layer] * (1.f / 8192.f);
  int tier = 0;
#pragma unroll
  for (int i = 0; i < 8; ++i) tier += (z >= d_BOUNDS[i]) ? 1 : 0;
  const float dsneg = expf(-36.f * (z - ZC_F) * (z - ZC_F));
  const float th0 = (tid < 60) ? theta[tid] : 0.f;
  const float c0 = __cosf(th0);
  float pc0 = (tid < 60) ? c0 : 0.f;
  float ps0 = (tid < 60) ? __sinf(th0) : 0.f;
  pc0 = wave_sum(pc0) * (1.f / 60.f);
  ps0 = wave_sum(ps0) * (1.f / 60.f);
  const float ch0 = sqrtf(pc0 * pc0 + ps0 * ps0);
  fe[tid] = (tid < 60) ? c0
          : (tid == 60) ? z
          : (tid == 61) ? ch0
          : (tid == 62) ? dsneg
                        : (float)(tier + 1) * (1.f / 9.f);
  __syncthreads();
  float a1 = b1[layer * 64 + tid];
#pragma unroll 8
  for (int k = 0; k < 64; ++k)
    a1 = fmaf(fe[k], W1[layer * 4096 + k * 64 + tid], a1);
  hh[tid] = gelu_exact(a1);
  __syncthreads();
  float a2 = b2[layer * 64 + tid];
#pragma unroll 8
  for (int k = 0; k < 64; ++k)
    a2 = fmaf(hh[k], W2[layer * 4096 + k * 64 + tid], a2);
  __syncthreads();
  fe[tid] = gelu_exact(a2);
  __syncthreads();
  if (tid < 6) {
    float a3 = b3[layer * 6 + tid] + prior[layer * 6 + tid];
#pragma unroll 8
    for (int k = 0; k < 64; ++k)
      a3 = fmaf(fe[k], W3[layer * 384 + k * 6 + tid], a3);
    lg[tid] = a3;
  }
  __syncthreads();
  int idx = 0;
  float best = -INFINITY;
#pragma unroll
  for (int m2 = 0; m2 < 6; ++m2)
    if (d_LEGAL[tier][m2] && lg[m2] > best) { best = lg[m2]; idx = m2; }
  const float par = d_PARITY[idx];
  const float coef = (idx == 1) ? 0.1f : ((idx == 5) ? -0.1f : 0.f);
  const bool dm = (idx == 4);
  const float ktot =
      (1.f + par * (aplK[layer * 6 + idx] * z) * 0.5f) * 0.1f * Kglob[layer] * (1.f / 60.f);
  const float omadd = aplOm[layer * 6 + idx] * par;

  // ---- state load ----
  float th[4][4], om[4][4];
#pragma unroll
  for (int m = 0; m < 4; ++m) {
    if (m == 3 && g == 3) {
#pragma unroll
      for (int r = 0; r < 4; ++r) { th[m][r] = 0.f; om[m][r] = 0.f; }
    } else {
      const float4 t4 = *reinterpret_cast<const float4*>(theta + b * 60 + 16 * m + 4 * g);
      const float4 o4 = *reinterpret_cast<const float4*>(omega + layer * 60 + 16 * m + 4 * g);
      const float ta[4] = {t4.x, t4.y, t4.z, t4.w};
      const float oa[4] = {o4.x, o4.y, o4.z, o4.w};
#pragma unroll
      for (int r = 0; r < 4; ++r) { th[m][r] = ta[r]; om[m][r] = 0.1f * (oa[r] + omadd); }
    }
  }
  // pre-mod coherence + mean per column
  float pcc = 0.f, pss = 0.f, psum = 0.f;
#pragma unroll
  for (int m = 0; m < 4; ++m)
#pragma unroll
    for (int r = 0; r < 4; ++r) {
      pcc += __cosf(th[m][r]);
      pss += __sinf(th[m][r]);
      psum += th[m][r];
    }
  pcc += __shfl_xor(pcc, 16); pcc += __shfl_xor(pcc, 32);
  pss += __shfl_xor(pss, 16); pss += __shfl_xor(pss, 32);
  psum += __shfl_xor(psum, 16); psum += __shfl_xor(psum, 32);
  const float mcp = (pcc - 4.f) * (1.f / 60.f);
  const float msp = pss * (1.f / 60.f);
  const float ch_pre = sqrtf(mcp * mcp + msp * msp);
  const float mean = psum * (1.f / 60.f);
  if (coef != 0.f) {
#pragma unroll
    for (int m = 0; m < 4; ++m)
#pragma unroll
      for (int r = 0; r < 4; ++r) {
        const int o = 16 * m + 4 * g + r;
        if (o < 60) th[m][r] += coef * __sinf(mean - th[m][r]);
      }
  }
  if (dm) {
    const float f = 0.05f * (1.f - ch_pre);
#pragma unroll
    for (int m = 0; m < 4; ++m) {
      if (m == 3 && g == 3) continue;
      const float4 n4 = *reinterpret_cast<const float4*>(noiseL + b * 60 + 16 * m + 4 * g);
      const float na[4] = {n4.x, n4.y, n4.z, n4.w};
#pragma unroll
      for (int r = 0; r < 4; ++r) th[m][r] = fmaf(f, na[r], th[m][r]);
    }
  }
  float s[4][4], cc[4][4];
#pragma unroll
  for (int m = 0; m < 4; ++m)
#pragma unroll
    for (int r = 0; r < 4; ++r) { s[m][r] = __sinf(th[m][r]); cc[m][r] = __cosf(th[m][r]); }

  // ---- A fragments from K (f32 -> bf16) ----
  union Frag { unsigned u[4]; bf16x8v v; };
  Frag Af[4][2];
#pragma unroll
  for (int m = 0; m < 4; ++m) {
    const int i = 16 * m + c;
#pragma unroll
    for (int kt = 0; kt < 2; ++kt) {
      if (i < 60) {
        const float* kp = K + layer * 3600 + i * 60 + 32 * kt + 8 * g;
        const float4 u0 = *reinterpret_cast<const float4*>(kp);
        float4 u1;
        if (kt == 1 && g == 3) u1 = make_float4(0.f, 0.f, 0.f, 0.f);
        else u1 = *reinterpret_cast<const float4*>(kp + 4);
        Af[m][kt].u[0] = pkbf(u0.x, u0.y); Af[m][kt].u[1] = pkbf(u0.z, u0.w);
        Af[m][kt].u[2] = pkbf(u1.x, u1.y); Af[m][kt].u[3] = pkbf(u1.z, u1.w);
      } else {
        Af[m][kt].u[0] = Af[m][kt].u[1] = Af[m][kt].u[2] = Af[m][kt].u[3] = 0u;
      }
    }
  }

  const int srcA = ((2 * g) & 3) * 16 + c;
  const int srcB = ((2 * g + 1) & 3) * 16 + c;
  const f32x4v z4 = {0.f, 0.f, 0.f, 0.f};

  for (int step = 0; step < 10; ++step) {
    unsigned sd[4][2], cd[4][2];
#pragma unroll
    for (int m = 0; m < 4; ++m)
#pragma unroll
      for (int p = 0; p < 2; ++p) {
        sd[m][p] = pkbf(s[m][2 * p], s[m][2 * p + 1]);
        cd[m][p] = pkbf(cc[m][2 * p], cc[m][2 * p + 1]);
      }
    union { unsigned u[4]; bf16x8v v; } BS[2], BC[2];
#pragma unroll
    for (int kt = 0; kt < 2; ++kt)
#pragma unroll
      for (int p = 0; p < 2; ++p) {
        unsigned a0 = (unsigned)__shfl((int)sd[2 * kt][p], srcA, 64);
        unsigned a1 = (unsigned)__shfl((int)sd[2 * kt + 1][p], srcA, 64);
        BS[kt].u[p] = hi ? a1 : a0;
        unsigned b0 = (unsigned)__shfl((int)sd[2 * kt][p], srcB, 64);
        unsigned b1 = (unsigned)__shfl((int)sd[2 * kt + 1][p], srcB, 64);
        BS[kt].u[2 + p] = hi ? b1 : b0;
        unsigned e0 = (unsigned)__shfl((int)cd[2 * kt][p], srcA, 64);
        unsigned e1 = (unsigned)__shfl((int)cd[2 * kt + 1][p], srcA, 64);
        BC[kt].u[p] = hi ? e1 : e0;
        unsigned f0 = (unsigned)__shfl((int)cd[2 * kt][p], srcB, 64);
        unsigned f1 = (unsigned)__shfl((int)cd[2 * kt + 1][p], srcB, 64);
        BC[kt].u[2 + p] = hi ? f1 : f0;
      }
    f32x4v P[4], Q[4];
#pragma unroll
    for (int m = 0; m < 4; ++m) {
      f32x4v t0 = __builtin_amdgcn_mfma_f32_16x16x32_bf16(Af[m][0].v, BS[0].v, z4, 0, 0, 0);
      P[m] = __builtin_amdgcn_mfma_f32_16x16x32_bf16(Af[m][1].v, BS[1].v, t0, 0, 0, 0);
      f32x4v t1 = __builtin_amdgcn_mfma_f32_16x16x32_bf16(Af[m][0].v, BC[0].v, z4, 0, 0, 0);
      Q[m] = __builtin_amdgcn_mfma_f32_16x16x32_bf16(Af[m][1].v, BC[1].v, t1, 0, 0, 0);
    }
#pragma unroll
    for (int m = 0; m < 4; ++m)
#pragma unroll
      for (int r = 0; r < 4; ++r) {
        const float csum = cc[m][r] * P[m][r] - s[m][r] * Q[m][r];
        const float d = fmaf(ktot, csum, om[m][r]);
        th[m][r] += d;
        const float d2 = d * d;
        const float sdl = d * (1.f - d2 * (1.f / 6.f));
        const float cdl = 1.f - d2 * 0.5f;
        const float sn = s[m][r] * cdl + cc[m][r] * sdl;
        cc[m][r] = cc[m][r] * cdl - s[m][r] * sdl;
        s[m][r] = sn;
      }
  }

  // epilogue: coherence + wrapped theta store + z accumulation
  float pc2 = 0.f, ps2 = 0.f;
#pragma unroll
  for (int m = 0; m < 4; ++m)
#pragma unroll
    for (int r = 0; r < 4; ++r) { pc2 += cc[m][r]; ps2 += s[m][r]; }
  pc2 += __shfl_xor(pc2, 16); pc2 += __shfl_xor(pc2, 32);
  ps2 += __shfl_xor(ps2, 16); ps2 += __shfl_xor(ps2, 32);
  const float mc2 = (pc2 - 4.f) * (1.f / 60.f);
  const float ms2 = ps2 * (1.f / 60.f);
  const float ch = sqrtf(mc2 * mc2 + ms2 * ms2);
#pragma unroll
  for (int m = 0; m < 4; ++m) {
    if (m == 3 && g == 3) continue;
    float w[4];
#pragma unroll
    for (int r = 0; r < 4; ++r) {
      const float t = th[m][r];
      w[r] = fmaf(-TWO_PI_F, rintf(t * INV_2PI_F), t);
    }
    *reinterpret_cast<float4*>(theta + b * 60 + 16 * m + 4 * g) =
        make_float4(w[0], w[1], w[2], w[3]);
  }
  if (layer < 3) {
    const float tot = wave_sum(ch) * 0.25f;
    if (tid == 0) atomicAdd(slots + layer + 1, tot);
  }
}

// ---------------------------------------------------------------------------
// MFMA output: out = ([cos,sin] @ W_out + b_out) * coh. Reuses the kura
// shuffle block for B-frags; LDS transpose for coalesced stores.
// ---------------------------------------------------------------------------
__global__ __launch_bounds__(64) void out_mfma(
    const float* __restrict__ theta, const unsigned short* __restrict__ Aout,
    const float* __restrict__ b_out, float* __restrict__ out) {
  __shared__ __align__(16) float trans[16][256];
  const int tid = threadIdx.x;
  const int c = tid & 15, g = tid >> 4;
  const bool hi = (g >= 2);
  const int b0 = blockIdx.x * 16;
  const int b = b0 + c;
  float s[4][4], cc[4][4];
  float pc = 0.f, ps = 0.f;
#pragma unroll
  for (int m = 0; m < 4; ++m) {
    float ta[4];
    if (m == 3 && g == 3) { ta[0] = ta[1] = ta[2] = ta[3] = 0.f; }
    else {
      const float4 t4 = *reinterpret_cast<const float4*>(theta + b * 60 + 16 * m + 4 * g);
      ta[0] = t4.x; ta[1] = t4.y; ta[2] = t4.z; ta[3] = t4.w;
    }
#pragma unroll
    for (int r = 0; r < 4; ++r) {
      s[m][r] = __sinf(ta[r]); cc[m][r] = __cosf(ta[r]);
      pc += cc[m][r]; ps += s[m][r];
    }
  }
  pc += __shfl_xor(pc, 16); pc += __shfl_xor(pc, 32);
  ps += __shfl_xor(ps, 16); ps += __shfl_xor(ps, 32);
  const float mc = (pc - 4.f) * (1.f / 60.f);
  const float ms = ps * (1.f / 60.f);
  const float ch = sqrtf(mc * mc + ms * ms);

  unsigned sd[4][2], cd[4][2];
#pragma unroll
  for (int m = 0; m < 4; ++m)
#pragma unroll
    for (int p = 0; p < 2; ++p) {
      sd[m][p] = pkbf(s[m][2 * p], s[m][2 * p + 1]);
      cd[m][p] = pkbf(cc[m][2 * p], cc[m][2 * p + 1]);
    }
  const int srcA = ((2 * g) & 3) * 16 + c;
  const int srcB = ((2 * g + 1) & 3) * 16 + c;
  union { unsigned u[4]; bf16x8v v; } BS[2], BC[2];
#pragma unroll
  for (int kt = 0; kt < 2; ++kt)
#pragma unroll
    for (int p = 0; p < 2; ++p) {
      unsigned a0 = (unsigned)__shfl((int)sd[2 * kt][p], srcA, 64);
      unsigned a1 = (unsigned)__shfl((int)sd[2 * kt + 1][p], srcA, 64);
      BS[kt].u[p] = hi ? a1 : a0;
      unsigned b1u = (unsigned)__shfl((int)sd[2 * kt + 1][p], srcB, 64);
      unsigned b0u = (unsigned)__shfl((int)sd[2 * kt][p], srcB, 64);
      BS[kt].u[2 + p] = hi ? b1u : b0u;
      unsigned e0 = (unsigned)__shfl((int)cd[2 * kt][p], srcA, 64);
      unsigned e1 = (unsigned)__shfl((int)cd[2 * kt + 1][p], srcA, 64);
      BC[kt].u[p] = hi ? e1 : e0;
      unsigned f0 = (unsigned)__shfl((int)cd[2 * kt][p], srcB, 64);
      unsigned f1 = (unsigned)__shfl((int)cd[2 * kt + 1][p], srcB, 64);
      BC[kt].u[2 + p] = hi ? f1 : f0;
    }
  const f32x4v z4 = {0.f, 0.f, 0.f, 0.f};
#pragma unroll
  for (int mp = 0; mp < 16; ++mp) {
    const unsigned short* ap = Aout + (16 * mp + c) * 128 + 8 * g;
    const bf16x8v A0 = *reinterpret_cast<const bf16x8v*>(ap);
    const bf16x8v A1 = *reinterpret_cast<const bf16x8v*>(ap + 32);
    const bf16x8v A2 = *reinterpret_cast<const bf16x8v*>(ap + 64);
    const bf16x8v A3 = *reinterpret_cast<const bf16x8v*>(ap + 96);
    f32x4v d = __builtin_amdgcn_mfma_f32_16x16x32_bf16(A0, BC[0].v, z4, 0, 0, 0);
    d = __builtin_amdgcn_mfma_f32_16x16x32_bf16(A1, BC[1].v, d, 0, 0, 0);
    d = __builtin_amdgcn_mfma_f32_16x16x32_bf16(A2, BS[0].v, d, 0, 0, 0);
    d = __builtin_amdgcn_mfma_f32_16x16x32_bf16(A3, BS[1].v, d, 0, 0, 0);
    const float4 bo = *reinterpret_cast<const float4*>(b_out + 16 * mp + 4 * g);
    *reinterpret_cast<float4*>(&trans[c][16 * mp + 4 * g]) =
        make_float4((d[0] + bo.x) * ch, (d[1] + bo.y) * ch,
                    (d[2] + bo.z) * ch, (d[3] + bo.w) * ch);
  }
  __syncthreads();
#pragma unroll
  for (int row = 0; row < 16; ++row) {
    const float4 v = *reinterpret_cast<const float4*>(&trans[row][4 * tid]);
    *reinterpret_cast<float4*>(out + (b0 + row) * 256 + 4 * tid) = v;
  }
}

// ---------------------------------------------------------------------------
// Workspace: theta f32[491520] @0; A-region 32768 ushorts @ float 491520
// (Aenc for enc, overwritten by Aout after enc). Total 2,031,616 B.
// z-slots live in d_out[0:8] (memset at graph start; overwritten by out_mfma).
// ---------------------------------------------------------------------------
extern "C" void kernel_launch(void* const* d_in, const int* in_sizes, int n_in,
                              void* d_out, int out_size, void* d_ws, size_t ws_size,
                              hipStream_t stream) {
  const float* x     = (const float*)d_in[0];
  const float* W_enc = (const float*)d_in[1];
  const float* b_enc = (const float*)d_in[2];
  const float* K     = (const float*)d_in[3];
  const float* omega = (const float*)d_in[4];
  const float* Kglob = (const float*)d_in[5];
  const float* aplK  = (const float*)d_in[6];
  const float* aplOm = (const float*)d_in[7];
  const float* W1    = (const float*)d_in[8];
  const float* b1    = (const float*)d_in[9];
  const float* W2    = (const float*)d_in[10];
  const float* b2    = (const float*)d_in[11];
  const float* W3    = (const float*)d_in[12];
  const float* b3    = (const float*)d_in[13];
  const float* prior = (const float*)d_in[14];
  const float* noise = (const float*)d_in[15];
  const float* W_out = (const float*)d_in[16];
  const float* b_out = (const float*)d_in[17];

  float* ws = (float*)d_ws;
  float* theta = ws;
  unsigned short* Areg = (unsigned short*)(ws + 491520);
  float* slots = (float*)d_out;

  hipMemsetAsync(d_out, 0, 32, stream);
  prep_A_enc<<<32, 256, 0, stream>>>(W_enc, Areg);
  enc_mfma<<<512, 64, 0, stream>>>(x, Areg, b_enc, theta, slots);
  prep_A_out<<<32, 256, 0, stream>>>(W_out, Areg);
  for (int l = 0; l < 4; ++l) {
    kura_mfma<<<512, 64, 0, stream>>>(theta, noise + (size_t)l * 491520,
                                      K, omega, Kglob, aplK, aplOm,
                                      W1, b1, W2, b2, W3, b3, prior,
                                      slots, l);
  }
  out_mfma<<<512, 64, 0, stream>>>(theta, Areg, b_out, (float*)d_out);
}